// Round 5
// baseline (168.324 us; speedup 1.0000x reference)
//
#include <hip/hip_runtime.h>
#include <math.h>

#define Bb 16
#define Nn 1024
#define Dd 16
#define NL 15

typedef __attribute__((ext_vector_type(8))) short short8;
typedef __attribute__((ext_vector_type(16))) float f32x16;
typedef __attribute__((ext_vector_type(4))) unsigned uint4v;
typedef __attribute__((ext_vector_type(2))) float float2v;

#if __has_builtin(__builtin_amdgcn_exp2f)
#define EXP2(x) __builtin_amdgcn_exp2f(x)
#else
#define EXP2(x) exp2f(x)
#endif

// ---------------- workspace layout (split path) ----------------
// Kg : [NL*Bb][1024][16] bf16   (row-major, 32B/key)
// Vg : [NL*Bb][16][1024] bf16   (V^T, keys vperm'd within 16-blocks)
// Qg : [NL*Bb][1024][16] bf16   (scaled by qscale, round-half-up)
// ones: 1088 bf16(1.0)
#define PROJ_SZ ((size_t)NL * Bb * 1024 * 16)          // elements per tensor
#define WS_NEED (3 * PROJ_SZ * 2 + 1088 * 2)

// ---------------- old-path LDS layout (fallback, verified R9) ----------------
#define VSTR 1040
#define V_OFF 32768
#define ONES_OFF 66048
#define RS_OFF 69632
#define LDS_TOTAL 73728

// round-half-up fp32->bf16 (proj staging)
__device__ __forceinline__ unsigned pack2bf(float a, float b) {
    unsigned ua = __float_as_uint(a) + 0x8000u;
    unsigned ub = __float_as_uint(b) + 0x8000u;
    return (ua >> 16) | (ub & 0xffff0000u);
}
__device__ __forceinline__ unsigned short bf1(float a) {
    return (unsigned short)((__float_as_uint(a) + 0x8000u) >> 16);
}

// exp2 both (hardware trans), truncate-pack to bf16 pair (fallback path only)
__device__ __forceinline__ unsigned expperm(float x, float y) {
    unsigned ex = __float_as_uint(EXP2(x));
    unsigned ey = __float_as_uint(EXP2(y));
#if __has_builtin(__builtin_amdgcn_perm)
    return __builtin_amdgcn_perm(ey, ex, 0x07060302);   // {ey.hi16, ex.hi16}
#else
    return (ex >> 16) | (ey & 0xffff0000u);
#endif
}

// R14: VALU-only packed exp2 pair -> truncated bf16 pair in one u32.
// Rationale: R9/R11/R12/R13 all pinned at ~61us with MfmaUtil 15.5 + VALUBusy
// 39.5 + ~45% unattributed stall — consistent with the per-CU transcendental
// unit at ~84% (4 SIMDs x 16 v_exp x 8cyc per 608-cyc chunk-slot). This
// removes ALL in-loop v_exp_f32: magic-rint + degree-4 2^f poly on [-.5,.5]
// (rel err 5e-5 << bf16 ULP 4e-3, so P bits match the old path to <=1 ULP)
// + integer exponent insert. float2v arithmetic -> v_pk_fma_f32 (gfx90a+).
// No clamp: |scores| < ~10 (0.05-scale weights); an exponent wrap would blow
// absmax visibly. Valid for rint(x) in (-126, 127).
__device__ __forceinline__ unsigned exp2pk(float x, float y) {
    const float2v MAGIC = {12582912.f, 12582912.f};     // 1.5 * 2^23
    const float2v C4 = {0.009618129f, 0.009618129f};    // ln2^4/24
    const float2v C3 = {0.055504109f, 0.055504109f};    // ln2^3/6
    const float2v C2 = {0.240226507f, 0.240226507f};    // ln2^2/2
    const float2v C1 = {0.693147181f, 0.693147181f};    // ln2
    const float2v ONE = {1.f, 1.f};
    float2v v = {x, y};
    float2v t = v + MAGIC;            // bits(t) = 0x4B400000 + rint(v)
    float2v u = t - MAGIC;            // u = rint(v), exact
    float2v f = v - u;                // f in [-0.5, 0.5], exact
    float2v p = f * C4 + C3;
    p = f * p + C2;
    p = f * p + C1;
    p = f * p + ONE;                  // p ~= 2^f, rel err <= 5e-5
    unsigned e0 = __float_as_uint(t.x) << 23;   // (n mod 512) << 23
    unsigned e1 = __float_as_uint(t.y) << 23;
    unsigned r0 = __float_as_uint(p.x) + e0;    // ldexp(p, n) bitwise
    unsigned r1 = __float_as_uint(p.y) + e1;
#if __has_builtin(__builtin_amdgcn_perm)
    return __builtin_amdgcn_perm(r1, r0, 0x07060302);   // {r1.hi16, r0.hi16}
#else
    return (r0 >> 16) | (r1 & 0xffff0000u);
#endif
}

// key permutation within a 16-block so a b128 at short-offset 8h yields keys
// {4h+0..3, 8+4h+0..3} (the 32x32x16 A-frag key order of the C->A identity)
__device__ __forceinline__ int vperm(int m) {
    return (m & 3) + ((m & 8) >> 1) + ((m & 4) << 1);
}

// ISA-pinned 16-B global load: volatile asm cannot be sunk/re-scheduled by
// hipcc (R12 lesson: plain loads get sunk to their uses, exposing L2 latency
// every chunk). NOTE: result regs are NOT valid until a manual s_waitcnt —
// vmcnt is the only scoreboard; never copy/read before the counted wait.
__device__ __forceinline__ uint4v gld16(const void* p) {
    uint4v r;
    asm volatile("global_load_dwordx4 %0, %1, off" : "=v"(r) : "v"(p));
    return r;
}
// counted wait + scheduling fence (rule #18: sched_barrier after asm waitcnt)
#define WAITV3() do { asm volatile("s_waitcnt vmcnt(3)" ::: "memory"); \
                      __builtin_amdgcn_sched_barrier(0); } while (0)

__device__ __forceinline__ void project(const float* __restrict__ xrow,
                                        const float* __restrict__ W,
                                        const float* __restrict__ bias,
                                        int i, float* __restrict__ q) {
#pragma unroll
    for (int r = 0; r < 16; r++) q[r] = 0.f;
    for (int c = 0; c < i; c++) {
        float xc = xrow[c];
#pragma unroll
        for (int r = 0; r < 16; r++) q[r] = fmaf(xc, W[r * 16 + c], q[r]);
    }
#pragma unroll
    for (int r = 0; r < 16; r++) q[r] = (r < i) ? (q[r] + bias[r]) : 0.f;
}

__device__ __forceinline__ void load_row16(const float* __restrict__ p, float* __restrict__ x) {
    const float4* xp = (const float4*)p;
    float4 a = xp[0], b = xp[1], c = xp[2], d = xp[3];
    x[0]=a.x; x[1]=a.y; x[2]=a.z; x[3]=a.w;
    x[4]=b.x; x[5]=b.y; x[6]=b.z; x[7]=b.w;
    x[8]=c.x; x[9]=c.y; x[10]=c.z; x[11]=c.w;
    x[12]=d.x; x[13]=d.y; x[14]=d.z; x[15]=d.w;
}

// ---------------------------------------------------------------------------
// Layer 0 (FALLBACK PATH ONLY): Z col 0 + logdet = -alpha0.
// On the split path this work is folded into gf_proj's l==0 blocks.
// ---------------------------------------------------------------------------
__global__ void gf_init(const float* __restrict__ X, const float* __restrict__ ip,
                        float* __restrict__ out) {
    int idx = blockIdx.x * blockDim.x + threadIdx.x;
    if (idx >= Bb * Nn) return;
    float mu = ip[0], alpha = ip[1];
    float x0 = X[(size_t)idx * Dd];
    out[(size_t)idx * Dd] = (x0 - mu) * __expf(-alpha);
    out[(size_t)Bb * Nn * Dd + idx] = -alpha;
}

// ---------------------------------------------------------------------------
// Kernel A: projections -> global bf16 (Q scaled, K rows, V^T perm'd via LDS
// bounce so global writes are coalesced 32-B segments).
// 512-thread blocks, grid (NL, Bb, 2) = 480 blocks. Layer-0 init + ones-fill
// folded into the l==0 blocks.
// ---------------------------------------------------------------------------
__global__ void gf_proj(const float* __restrict__ X, const float* __restrict__ ip,
                        const float* __restrict__ Wq, const float* __restrict__ bq,
                        const float* __restrict__ Wk, const float* __restrict__ bk,
                        const float* __restrict__ Wv, const float* __restrict__ bv,
                        unsigned short* __restrict__ Kg,
                        unsigned short* __restrict__ Vg,
                        unsigned short* __restrict__ Qg,
                        unsigned short* __restrict__ onesb,
                        float* __restrict__ out) {
    __shared__ unsigned short Vt[16 * 520];    // 512 cols + 8 pad
    const int l = blockIdx.x, b = blockIdx.y, z = blockIdx.z, i = l + 1;
    const int t = threadIdx.x;                 // 0..511
    const int n = z * 512 + t;                 // token
    const size_t lb = (size_t)(l * Bb + b);
    const float qscale = 1.4426950408889634f * rsqrtf((float)i);

    const float* Xb  = X  + (size_t)b * Nn * Dd;
    const float* wq  = Wq + l * 256;  const float* bql = bq + l * 16;
    const float* wk  = Wk + l * 256;  const float* bkl = bk + l * 16;
    const float* wvp = Wv + l * 256;  const float* bvl = bv + l * 16;

    float xr[16]; load_row16(Xb + (size_t)n * Dd, xr);
    float tmp[16];

    project(xr, wk, bkl, i, tmp);
    {
        unsigned u[8];
#pragma unroll
        for (int r = 0; r < 8; r++) u[r] = pack2bf(tmp[2*r], tmp[2*r+1]);
        uint4* kd = (uint4*)(Kg + (lb * 1024 + n) * 16);
        kd[0] = make_uint4(u[0], u[1], u[2], u[3]);
        kd[1] = make_uint4(u[4], u[5], u[6], u[7]);
    }

    project(xr, wvp, bvl, i, tmp);
    {
        const int col = (t & ~15) + vperm(t & 15);
#pragma unroll
        for (int d = 0; d < 16; d++) Vt[d * 520 + col] = bf1(tmp[d]);
    }

    project(xr, wq, bql, i, tmp);
    {
        unsigned u[8];
#pragma unroll
        for (int r = 0; r < 8; r++) u[r] = pack2bf(tmp[2*r] * qscale, tmp[2*r+1] * qscale);
        uint4* qd = (uint4*)(Qg + (lb * 1024 + n) * 16);
        qd[0] = make_uint4(u[0], u[1], u[2], u[3]);
        qd[1] = make_uint4(u[4], u[5], u[6], u[7]);
    }

    if (l == 0) {                              // folded layer-0 init
        const float mu = ip[0], al = ip[1];
        out[((size_t)(b * Nn + n)) * Dd] = (xr[0] - mu) * __expf(-al);
        out[(size_t)Bb * Nn * Dd + b * Nn + n] = -al;
        if (b == 0 && z == 0) {
            onesb[t] = 0x3F80; onesb[512 + t] = 0x3F80;
            if (t < 64) onesb[1024 + t] = 0x3F80;
        }
    }

    __syncthreads();
    {   // coalesced V^T copy-out: thread (d=t>>5, seg=t&31) -> 32 contig bytes
        const int d = t >> 5, seg = t & 31;
        const uint4* src = (const uint4*)(Vt + d * 520 + seg * 16);
        uint4* dst = (uint4*)(Vg + lb * (16 * 1024) + d * 1024 + z * 512 + seg * 16);
        dst[0] = src[0];
        dst[1] = src[1];
    }
}

// ---------------------------------------------------------------------------
// Kernel B: attention + epilogue. 256-thread blocks (4 waves), one 32-query
// stream per wave, 32 keys/iter from global (L2-resident), ISA-pipelined
// (pinned loads + counted vmcnt, unroll x2 static double-buffer).
// R14: exp2pk replaces v_exp_f32 (see exp2pk comment) — attacks the per-CU
// shared trans-pipe saturation that held R9-R13 at ~61us.
// grid: 1920 linear blocks, bijectively swizzled (240 = 8*30) for L2 reuse.
// ---------------------------------------------------------------------------
__launch_bounds__(256, 4)
__global__ void gf_attn(const float* __restrict__ X,
                        const unsigned short* __restrict__ Kg,
                        const unsigned short* __restrict__ Vg,
                        const unsigned short* __restrict__ Qg,
                        const unsigned short* __restrict__ onesb,
                        const float* __restrict__ Wo, const float* __restrict__ bo,
                        const float* __restrict__ Wf, const float* __restrict__ bf,
                        float* __restrict__ out) {
    __shared__ float Osh[4 * 32 * 17];
    __shared__ float Rsh[4 * 32];

    // bijective XCD swizzle: bx=(gl*8+z)*8+c  <->  G=c*30+gl, slice z
    const int bx = blockIdx.x;
    const int c8 = bx & 7, kk = bx >> 3;
    const int G = c8 * 30 + (kk >> 3);
    const int z = kk & 7;
    const int l = G % NL, b = G / NL, i = l + 1;

    const int t = threadIdx.x;
    const int wid = t >> 6, lane = t & 63;
    const int q31 = lane & 31, h = lane >> 5;
    const size_t lb = (size_t)(l * Bb + b);
    const int qbase = z * 128 + wid * 32;

    // Q B-frag: lane(q31,h) = Q[qbase+q31][8h..8h+7] (pre-scaled bf16)
    short8 qf = *(const short8*)(Qg + (lb * 1024 + qbase + q31) * 16 + 8 * h);

    // A-frag pointer: K[key q31+kn][8h..]; B-frag pointer: V^T row d=q31
    // (perm'd) or ones for q31>=16 (rs via col 16 of D).
    const unsigned short* Kp = Kg + (lb * 1024 + q31) * 16 + 8 * h;
    const unsigned short* Vp = ((q31 < 16) ? (Vg + (lb * 16 + q31) * 1024)
                                           : onesb) + 8 * h;

    const f32x16 zf16 = {};
    f32x16 D0 = {}, D1 = {};
    f32x16 s_cur, s_nxt;

    // double-buffered fragment slots (uint4v; bit_cast at use, AFTER wait)
    uint4v k0u, k1u, v00u, v01u, v10u, v11u;

    // prologue: chunk0 -> slot0, chunk1 -> slot1; wait chunk0; QK0.
    k0u  = gld16(Kp);
    v00u = gld16(Vp);
    v01u = gld16(Vp + 16);
    k1u  = gld16(Kp + 32 * 16);
    v10u = gld16(Vp + 32);
    v11u = gld16(Vp + 48);
    WAITV3();                                  // k0u, v00u, v01u arrived
    s_cur = __builtin_amdgcn_mfma_f32_32x32x16_bf16(
                __builtin_bit_cast(short8, k0u), qf, zf16, 0, 0, 0);
    // loop entry invariant: outstanding = {K(c+1), V0(c+1), V1(c+1)} = 3

#pragma unroll 1
    for (int c = 0; c < 32; c += 2) {
        // ---- even: PV chunk c (slot0 V), QK chunk c+1 (slot1 K) ----
        {
            const int kn2 = ((c + 2) << 5) & (Nn - 1);
            k0u = gld16(Kp + (size_t)kn2 * 16);            // K(c+2); out=4
            WAITV3();                                      // K(c+1) arrived
            s_nxt = __builtin_amdgcn_mfma_f32_32x32x16_bf16(
                        __builtin_bit_cast(short8, k1u), qf, zf16, 0, 0, 0);
            {
                uint4v a0 = {exp2pk(s_cur[0], s_cur[1]), exp2pk(s_cur[2], s_cur[3]),
                             exp2pk(s_cur[4], s_cur[5]), exp2pk(s_cur[6], s_cur[7])};
                D0 = __builtin_amdgcn_mfma_f32_32x32x16_bf16(
                         __builtin_bit_cast(short8, a0),
                         __builtin_bit_cast(short8, v00u), D0, 0, 0, 0);
            }
            {
                uint4v a1 = {exp2pk(s_cur[8], s_cur[9]),  exp2pk(s_cur[10], s_cur[11]),
                             exp2pk(s_cur[12], s_cur[13]), exp2pk(s_cur[14], s_cur[15])};
                D1 = __builtin_amdgcn_mfma_f32_32x32x16_bf16(
                         __builtin_bit_cast(short8, a1),
                         __builtin_bit_cast(short8, v01u), D1, 0, 0, 0);
            }
            v00u = gld16(Vp + kn2);                        // V(c+2); out=5
            v01u = gld16(Vp + kn2 + 16);                   //         out=6 -> wait to 3
            WAITV3();                                      // V(c+1) arrived
            s_cur = s_nxt;                                 // scores chunk c+1
        }
        // ---- odd: PV chunk c+1 (slot1 V), QK chunk c+2 (slot0 K) ----
        {
            const int kn2 = ((c + 3) << 5) & (Nn - 1);
            k1u = gld16(Kp + (size_t)kn2 * 16);            // K(c+3)
            WAITV3();                                      // K(c+2) arrived
            s_nxt = __builtin_amdgcn_mfma_f32_32x32x16_bf16(
                        __builtin_bit_cast(short8, k0u), qf, zf16, 0, 0, 0);
            {
                uint4v a0 = {exp2pk(s_cur[0], s_cur[1]), exp2pk(s_cur[2], s_cur[3]),
                             exp2pk(s_cur[4], s_cur[5]), exp2pk(s_cur[6], s_cur[7])};
                D0 = __builtin_amdgcn_mfma_f32_32x32x16_bf16(
                         __builtin_bit_cast(short8, a0),
                         __builtin_bit_cast(short8, v10u), D0, 0, 0, 0);
            }
            {
                uint4v a1 = {exp2pk(s_cur[8], s_cur[9]),  exp2pk(s_cur[10], s_cur[11]),
                             exp2pk(s_cur[12], s_cur[13]), exp2pk(s_cur[14], s_cur[15])};
                D1 = __builtin_amdgcn_mfma_f32_32x32x16_bf16(
                         __builtin_bit_cast(short8, a1),
                         __builtin_bit_cast(short8, v11u), D1, 0, 0, 0);
            }
            v10u = gld16(Vp + kn2);                        // V(c+3)
            v11u = gld16(Vp + kn2 + 16);
            WAITV3();                                      // V(c+2) arrived
            s_cur = s_nxt;
        }
    }
    // 3 dangling wrap-around loads remain outstanding; __syncthreads below
    // drains vmcnt(0) (compiler-inserted), and all targets are dead regs.

    // ---- stage O (C-layout -> [q_local][d] stride 17) + rs; wave-local ----
    float* Ow = Osh + wid * (32 * 17);
    if (q31 < 16) {
#pragma unroll
        for (int r = 0; r < 16; r++) {
            int m = (r & 3) + 8 * (r >> 2) + 4 * h;   // query row in this wave
            Ow[m * 17 + q31] = D0[r] + D1[r];
        }
    }
    if (q31 == 16) {                      // col 16 of D = sum of P = rs
        float* Rw = Rsh + wid * 32;
#pragma unroll
        for (int r = 0; r < 16; r++) {
            int m = (r & 3) + 8 * (r >> 2) + 4 * h;
            Rw[m] = D0[r] + D1[r];
        }
    }
    __syncthreads();

    // ---------------- epilogue (threads t<128; query qn = z*128+t) ----------
    if (t < 128) {
        const int qn = z * 128 + t;
        const float invq = 0.6931471805599453f * sqrtf((float)i);  // 1/qscale

        // reconstruct q from Qg (bf16-rounded, exactly what the MFMA saw)
        float a[16];
        {
            const uint4* qp = (const uint4*)(Qg + (lb * 1024 + qn) * 16);
            uint4 u0 = qp[0], u1 = qp[1];
            unsigned uw[8] = {u0.x, u0.y, u0.z, u0.w, u1.x, u1.y, u1.z, u1.w};
#pragma unroll
            for (int r = 0; r < 8; r++) {
                a[2*r]     = __uint_as_float(uw[r] << 16) * invq;
                a[2*r + 1] = __uint_as_float(uw[r] & 0xffff0000u) * invq;
            }
        }

        const float* orow = Osh + (t >> 5) * (32 * 17) + (t & 31) * 17;
        const float  inv  = 1.f / Rsh[(t >> 5) * 32 + (t & 31)];
#pragma unroll
        for (int cc = 0; cc < 16; cc++) a[cc] += orow[cc] * inv;

        const float* wo  = Wo + l * 256;  const float* bol = bo + l * 16;
        const float* wf  = Wf + l * 32;   const float* bfl = bf + l * 2;

        float tt[16];
#pragma unroll
        for (int r = 0; r < 16; r++) {
            float acc = bol[r];
#pragma unroll
            for (int cc = 0; cc < 16; cc++) acc = fmaf(a[cc], wo[r * 16 + cc], acc);
            tt[r] = fmaxf(acc, 0.f);
        }
#pragma unroll
        for (int r = 0; r < 16; r++) a[r] += (r < i) ? tt[r] : 0.f;

        float mu = bfl[0], al = bfl[1];
#pragma unroll
        for (int cc = 0; cc < 16; cc++) {
            mu = fmaf(a[cc], wf[cc], mu);
            al = fmaf(a[cc], wf[16 + cc], al);
        }
        const float xi = X[((size_t)b * Nn + qn) * Dd + i];
        out[((size_t)(b * Nn + qn)) * Dd + i] = (xi - mu) * __expf(-al);
        atomicAdd(out + (size_t)Bb * Nn * Dd + b * Nn + qn, -al);
    }
}

// ---------------------------------------------------------------------------
// OLD path (verified R9, 63us dispatch): fused staged-LDS kernel. Used when
// the workspace is too small for the split path.
// ---------------------------------------------------------------------------
__launch_bounds__(1024, 4)
__global__ void gf_fused(const float* __restrict__ X,
                         const float* __restrict__ Wq, const float* __restrict__ bq,
                         const float* __restrict__ Wk, const float* __restrict__ bk,
                         const float* __restrict__ Wv, const float* __restrict__ bv,
                         const float* __restrict__ Wo, const float* __restrict__ bo,
                         const float* __restrict__ Wf, const float* __restrict__ bf,
                         float* __restrict__ out) {
    extern __shared__ char smem[];
    const int l = blockIdx.x, b = blockIdx.y, i = l + 1;
    const int t = threadIdx.x;
    const int wid = t >> 6, lane = t & 63;
    const int q31 = lane & 31, h = lane >> 5;
    const float qscale = 1.4426950408889634f * rsqrtf((float)i);

    unsigned short* Ksh  = (unsigned short*)smem;
    unsigned short* Vsh  = (unsigned short*)(smem + V_OFF);
    unsigned short* Ones = (unsigned short*)(smem + ONES_OFF);

    const float* Xb  = X  + (size_t)b * Nn * Dd;
    const float* wq  = Wq + l * 256;  const float* bql = bq + l * 16;
    const float* wk  = Wk + l * 256;  const float* bkl = bk + l * 16;
    const float* wvp = Wv + l * 256;  const float* bvl = bv + l * 16;
    const float* wo  = Wo + l * 256;  const float* bol = bo + l * 16;
    const float* wf  = Wf + l * 32;   const float* bfl = bf + l * 2;

    unsigned qu[8];
    {
        float xr[16]; load_row16(Xb + (size_t)t * Dd, xr);
        float tmp[16];

        project(xr, wk, bkl, i, tmp);
        {
            unsigned u[8];
#pragma unroll
            for (int r = 0; r < 8; r++) u[r] = pack2bf(tmp[2*r], tmp[2*r+1]);
            uint4* kd = (uint4*)(Ksh + t * 16);
            kd[0] = make_uint4(u[0], u[1], u[2], u[3]);
            kd[1] = make_uint4(u[4], u[5], u[6], u[7]);
        }

        project(xr, wvp, bvl, i, tmp);
        {
            unsigned short* vcol = Vsh + (t & ~15) + vperm(t & 15);
#pragma unroll
            for (int d = 0; d < 16; d++) vcol[d * VSTR] = bf1(tmp[d]);
        }

        Ones[t] = 0x3F80;

        project(xr, wq, bql, i, tmp);
#pragma unroll
        for (int r = 0; r < 8; r++) qu[r] = pack2bf(tmp[2*r] * qscale, tmp[2*r+1] * qscale);
    }
    __syncthreads();

    short8 qf0, qf1;
    {
        unsigned d0[4], d1[4];
#pragma unroll
        for (int j = 0; j < 4; j++) {
            unsigned lo = __shfl(qu[j], q31);
            unsigned hi = __shfl(qu[4 + j], q31);
            d0[j] = h ? hi : lo;
            lo = __shfl(qu[j], 32 + q31);
            hi = __shfl(qu[4 + j], 32 + q31);
            d1[j] = h ? hi : lo;
        }
        uint4v v0 = {d0[0], d0[1], d0[2], d0[3]};
        uint4v v1 = {d1[0], d1[1], d1[2], d1[3]};
        qf0 = __builtin_bit_cast(short8, v0);
        qf1 = __builtin_bit_cast(short8, v1);
    }

    f32x16 zf16 = {};
    f32x16 D0 = {}, D1 = {};

    const unsigned short* Kp = Ksh + (size_t)q31 * 16 + h * 8;
    const unsigned short* Vp = ((q31 < 16) ? (Vsh + (size_t)q31 * VSTR) : Ones) + 8 * h;

    short8 kf  = *(const short8*)Kp;
    short8 vc0 = *(const short8*)(Vp);
    short8 vc1 = *(const short8*)(Vp + 16);

    for (int kb = 0; kb < Nn; kb += 32) {
        const int kn = (kb + 32) & (Nn - 1);
        short8 kfn = *(const short8*)(Kp + (size_t)kn * 16);
        short8 vn0 = *(const short8*)(Vp + kn);
        short8 vn1 = *(const short8*)(Vp + kn + 16);

        f32x16 s0 = __builtin_amdgcn_mfma_f32_32x32x16_bf16(kf, qf0, zf16, 0, 0, 0);
        f32x16 s1 = __builtin_amdgcn_mfma_f32_32x32x16_bf16(kf, qf1, zf16, 0, 0, 0);
        kf = kfn;

        {
            uint4v a0 = {expperm(s0[0], s0[1]), expperm(s0[2], s0[3]),
                         expperm(s0[4], s0[5]), expperm(s0[6], s0[7])};
            D0 = __builtin_amdgcn_mfma_f32_32x32x16_bf16(
                     __builtin_bit_cast(short8, a0), vc0, D0, 0, 0, 0);
            uint4v a1 = {expperm(s1[0], s1[1]), expperm(s1[2], s1[3]),
                         expperm(s1[4], s1[5]), expperm(s1[6], s1[7])};
            D1 = __builtin_amdgcn_mfma_f32_32x32x16_bf16(
                     __builtin_bit_cast(short8, a1), vc0, D1, 0, 0, 0);
        }
        {
            uint4v a0 = {expperm(s0[8], s0[9]),  expperm(s0[10], s0[11]),
                         expperm(s0[12], s0[13]), expperm(s0[14], s0[15])};
            D0 = __builtin_amdgcn_mfma_f32_32x32x16_bf16(
                     __builtin_bit_cast(short8, a0), vc1, D0, 0, 0, 0);
            uint4v a1 = {expperm(s1[8], s1[9]),  expperm(s1[10], s1[11]),
                         expperm(s1[12], s1[13]), expperm(s1[14], s1[15])};
            D1 = __builtin_amdgcn_mfma_f32_32x32x16_bf16(
                     __builtin_bit_cast(short8, a1), vc1, D1, 0, 0, 0);
        }
        vc0 = vn0; vc1 = vn1;
    }

    __syncthreads();

    float* Ow = (float*)smem + wid * (64 * 17);
    if (q31 < 16) {
#pragma unroll
        for (int r = 0; r < 16; r++) {
            int m = (r & 3) + 8 * (r >> 2) + 4 * h;
            Ow[m * 17 + q31]        = D0[r];
            Ow[(m + 32) * 17 + q31] = D1[r];
        }
    }
    float* Rw = (float*)(smem + RS_OFF) + wid * 64;
    if (q31 == 16) {
#pragma unroll
        for (int r = 0; r < 16; r++) {
            int m = (r & 3) + 8 * (r >> 2) + 4 * h;
            Rw[m]      = D0[r];
            Rw[32 + m] = D1[r];
        }
    }

    {
        const float invq = 0.6931471805599453f * sqrtf((float)i);

        float a[16];
#pragma unroll
        for (int r = 0; r < 8; r++) {
            a[2*r]     = __uint_as_float(qu[r] << 16) * invq;
            a[2*r + 1] = __uint_as_float(qu[r] & 0xffff0000u) * invq;
        }

        const float* orow = (const float*)smem + wid * (64 * 17) + lane * 17;
        const float  inv  = 1.f / Rw[lane];
#pragma unroll
        for (int c = 0; c < 16; c++) a[c] += orow[c] * inv;

        float tt[16];
#pragma unroll
        for (int r = 0; r < 16; r++) {
            float acc = bol[r];
#pragma unroll
            for (int c = 0; c < 16; c++) acc = fmaf(a[c], wo[r * 16 + c], acc);
            tt[r] = fmaxf(acc, 0.f);
        }
#pragma unroll
        for (int r = 0; r < 16; r++) a[r] += (r < i) ? tt[r] : 0.f;

        float mu = bfl[0], al = bfl[1];
#pragma unroll
        for (int c = 0; c < 16; c++) {
            mu = fmaf(a[c], wf[c], mu);
            al = fmaf(a[c], wf[16 + c], al);
        }
        const float xi = Xb[(size_t)t * Dd + i];
        out[((size_t)(b * Nn + t)) * Dd + i] = (xi - mu) * __expf(-al);
        atomicAdd(out + (size_t)Bb * Nn * Dd + b * Nn + t, -al);
    }
}

// ---------------------------------------------------------------------------
// Fallback path (R1): fp32 kernel, if big dynamic LDS unavailable
// ---------------------------------------------------------------------------
__launch_bounds__(512, 2)
__global__ void gf_layer_fb(const float* __restrict__ X,
                            const float* __restrict__ Wq, const float* __restrict__ bq,
                            const float* __restrict__ Wk, const float* __restrict__ bk,
                            const float* __restrict__ Wv, const float* __restrict__ bv,
                            const float* __restrict__ Wo, const float* __restrict__ bo,
                            const float* __restrict__ Wf, const float* __restrict__ bf,
                            float* __restrict__ out) {
    const int l = blockIdx.x, b = blockIdx.y, i = l + 1, t = threadIdx.x;
    const float rscale = rsqrtf((float)i);
    __shared__ float Ksh[512 * 16];
    __shared__ float Vsh[512 * 16];
    const float* Xb = X + (size_t)b * Nn * Dd;
    const float* wq = Wq + l * 256; const float* wk = Wk + l * 256;
    const float* wv = Wv + l * 256; const float* wo = Wo + l * 256;
    const float* wf = Wf + l * 32;
    const float* bql = bq + l * 16; const float* bkl = bk + l * 16;
    const float* bvl = bv + l * 16; const float* bol = bo + l * 16;
    const float* bfl = bf + l * 2;
    const int n0 = t, n1 = t + 512;
    float q0[16], q1[16], xi0, xi1;
    {
        float xr[16];
        load_row16(Xb + (size_t)n0 * Dd, xr); xi0 = xr[i]; project(xr, wq, bql, i, q0);
        load_row16(Xb + (size_t)n1 * Dd, xr); xi1 = xr[i]; project(xr, wq, bql, i, q1);
    }
    float o0[16], o1[16];
#pragma unroll
    for (int c = 0; c < 16; c++) { o0[c] = 0.f; o1[c] = 0.f; }
    float ls0 = 0.f, ls1 = 0.f;
    for (int ch = 0; ch < 2; ch++) {
        float kr[16], vr[16];
        {
            float kx[16];
            load_row16(Xb + (size_t)(ch * 512 + t) * Dd, kx);
            project(kx, wk, bkl, i, kr);
            project(kx, wv, bvl, i, vr);
        }
        __syncthreads();
#pragma unroll
        for (int j = 0; j < 4; j++) {
            ((float4*)&Ksh[t * 16])[j] = ((float4*)kr)[j];
            ((float4*)&Vsh[t * 16])[j] = ((float4*)vr)[j];
        }
        __syncthreads();
        for (int k = 0; k < 512; k++) {
            float kk[16], vv[16];
#pragma unroll
            for (int j = 0; j < 4; j++) ((float4*)kk)[j] = ((const float4*)&Ksh[k * 16])[j];
            float s0 = 0.f, s1 = 0.f;
#pragma unroll
            for (int c = 0; c < 16; c++) { s0 = fmaf(q0[c], kk[c], s0); s1 = fmaf(q1[c], kk[c], s1); }
            float p0 = __expf(s0 * rscale), p1 = __expf(s1 * rscale);
            ls0 += p0; ls1 += p1;
#pragma unroll
            for (int j = 0; j < 4; j++) ((float4*)vv)[j] = ((const float4*)&Vsh[k * 16])[j];
#pragma unroll
            for (int c = 0; c < 16; c++) { o0[c] = fmaf(p0, vv[c], o0[c]); o1[c] = fmaf(p1, vv[c], o1[c]); }
        }
        __syncthreads();
    }
    float* logdet = out + (size_t)Bb * Nn * Dd;
#pragma unroll
    for (int rowsel = 0; rowsel < 2; rowsel++) {
        const float* qr = rowsel ? q1 : q0; const float* orr = rowsel ? o1 : o0;
        float lsum = rowsel ? ls1 : ls0; float xin = rowsel ? xi1 : xi0;
        int n = rowsel ? n1 : n0;
        float a[16]; float inv = 1.f / lsum;
#pragma unroll
        for (int c = 0; c < 16; c++) a[c] = qr[c] + orr[c] * inv;
        float tt[16];
#pragma unroll
        for (int r = 0; r < 16; r++) {
            float acc = bol[r];
#pragma unroll
            for (int c = 0; c < 16; c++) acc = fmaf(a[c], wo[r * 16 + c], acc);
            tt[r] = fmaxf(acc, 0.f);
        }
#pragma unroll
        for (int r = 0; r < 16; r++) a[r] += (r < i) ? tt[r] : 0.f;
        float mu = bfl[0], al = bfl[1];
#pragma unroll
        for (int c = 0; c < 16; c++) { mu = fmaf(a[c], wf[c], mu); al = fmaf(a[c], wf[16 + c], al); }
        out[((size_t)(b * Nn + n)) * Dd + i] = (xin - mu) * __expf(-al);
        atomicAdd(logdet + b * Nn + n, -al);
    }
}

extern "C" void kernel_launch(void* const* d_in, const int* in_sizes, int n_in,
                              void* d_out, int out_size, void* d_ws, size_t ws_size,
                              hipStream_t stream) {
    const float* X  = (const float*)d_in[0];
    const float* ip = (const float*)d_in[1];
    const float* Wq = (const float*)d_in[2];
    const float* bq = (const float*)d_in[3];
    const float* Wk = (const float*)d_in[4];
    const float* bk = (const float*)d_in[5];
    const float* Wv = (const float*)d_in[6];
    const float* bv = (const float*)d_in[7];
    const float* Wo = (const float*)d_in[8];
    const float* bo = (const float*)d_in[9];
    const float* Wf = (const float*)d_in[10];
    const float* bf = (const float*)d_in[11];
    float* out = (float*)d_out;

    if (ws_size >= WS_NEED && d_ws != nullptr) {
        unsigned short* Kg    = (unsigned short*)d_ws;
        unsigned short* Vg    = Kg + PROJ_SZ;
        unsigned short* Qg    = Vg + PROJ_SZ;
        unsigned short* onesb = Qg + PROJ_SZ;

        gf_proj<<<dim3(NL, Bb, 2), 512, 0, stream>>>(X, ip, Wq, bq, Wk, bk, Wv, bv,
                                                     Kg, Vg, Qg, onesb, out);
        gf_attn<<<NL * Bb * 8, 256, 0, stream>>>(X, Kg, Vg, Qg, onesb,
                                                 Wo, bo, Wf, bf, out);
        return;
    }

    gf_init<<<(Bb * Nn + 255) / 256, 256, 0, stream>>>(X, ip, out);

    hipError_t e = hipFuncSetAttribute((const void*)gf_fused,
                                       hipFuncAttributeMaxDynamicSharedMemorySize,
                                       LDS_TOTAL);
    if (e == hipSuccess) {
        gf_fused<<<dim3(NL, Bb), 1024, LDS_TOTAL, stream>>>(
            X, Wq, bq, Wk, bk, Wv, bv, Wo, bo, Wf, bf, out);
    } else {
        gf_layer_fb<<<dim3(NL, Bb), 512, 0, stream>>>(
            X, Wq, bq, Wk, bk, Wv, bv, Wo, bo, Wf, bf, out);
    }
}

// Round 6
// 134.853 us; speedup vs baseline: 1.2482x; 1.2482x over previous
//
#include <hip/hip_runtime.h>
#include <math.h>

#define Bb 16
#define Nn 1024
#define Dd 16
#define NL 15

typedef __attribute__((ext_vector_type(8))) short short8;
typedef __attribute__((ext_vector_type(16))) float f32x16;
typedef __attribute__((ext_vector_type(4))) unsigned uint4v;

#if __has_builtin(__builtin_amdgcn_exp2f)
#define EXP2(x) __builtin_amdgcn_exp2f(x)
#else
#define EXP2(x) exp2f(x)
#endif

// LDS layout (dynamic, 73728 B, 1 block/CU, 16 waves):
//   K    : [1024 keys][16 shorts]          offset 0      32768 B
//   V^T  : [16 d][VSTR=1040 shorts]        offset 32768  33280 B (2080-B rows:
//          16B-aligned; b128 V-frag reads are 4-phase bank-balanced)
//          V keys PRE-PERMUTED per 16-block (vperm) so one b128 = one B-frag
//   ones : [1024 shorts] bf16(1.0)         offset 66048   2048 B (loop-only;
//          overlaid by O after the barrier)
//   O    : 16 waves x [64 q][17 f32]       offset 0      69632 B (overlays
//          K+V+ones after the loop barrier)
//   rs   : 16 waves x [64 f32]             offset 69632   4096 B
// R15 session summary (why this structure):
//   R10 qh-split 8 w/SIMD  -> VGPR cap 64, spills, 435us (REJECTED)
//   R11 split proj/attn via global bf16 -> attn 64.8us == fused; proj adds
//       ~20us kernel + ~10us dispatch overhead (REJECTED: totals 160-168)
//   R12/R13 SW/ISA pipelining of attn loop -> 60.8us, no change (latency
//       theory falsified; loads were never the binding resource)
//   R14 VALU poly exp -> VALUBusy 58%, 73.7us (trans-pipe theory falsified;
//       exp-on-trans is cheaper than exp-on-VALU; VALU issue near-binding)
//   => the ~61-63us loop is exp-issue + VALU bound; exp count is exact-
//      softmax-irreducible. This round: R9 kernel + T5 s_setprio on MFMAs.
#define VSTR 1040
#define V_OFF 32768
#define ONES_OFF 66048
#define RS_OFF 69632
#define LDS_TOTAL 73728

// round-half-up fp32->bf16 (proj staging)
__device__ __forceinline__ unsigned pack2bf(float a, float b) {
    unsigned ua = __float_as_uint(a) + 0x8000u;
    unsigned ub = __float_as_uint(b) + 0x8000u;
    return (ua >> 16) | (ub & 0xffff0000u);
}
__device__ __forceinline__ unsigned short bf1(float a) {
    return (unsigned short)((__float_as_uint(a) + 0x8000u) >> 16);
}

// exp2 both, truncate-pack to bf16 pair in ONE v_perm_b32
__device__ __forceinline__ unsigned expperm(float x, float y) {
    unsigned ex = __float_as_uint(EXP2(x));
    unsigned ey = __float_as_uint(EXP2(y));
#if __has_builtin(__builtin_amdgcn_perm)
    return __builtin_amdgcn_perm(ey, ex, 0x07060302);   // {ey.hi16, ex.hi16}
#else
    return (ex >> 16) | (ey & 0xffff0000u);
#endif
}

// key permutation within a 16-block so a b128 at short-offset 8h yields keys
// {4h+0..3, 8+4h+0..3} (the 32x32x16 A-frag key order of the C->A identity)
__device__ __forceinline__ int vperm(int m) {
    return (m & 3) + ((m & 8) >> 1) + ((m & 4) << 1);
}

__device__ __forceinline__ void project(const float* __restrict__ xrow,
                                        const float* __restrict__ W,
                                        const float* __restrict__ bias,
                                        int i, float* __restrict__ q) {
#pragma unroll
    for (int r = 0; r < 16; r++) q[r] = 0.f;
    for (int c = 0; c < i; c++) {
        float xc = xrow[c];
#pragma unroll
        for (int r = 0; r < 16; r++) q[r] = fmaf(xc, W[r * 16 + c], q[r]);
    }
#pragma unroll
    for (int r = 0; r < 16; r++) q[r] = (r < i) ? (q[r] + bias[r]) : 0.f;
}

__device__ __forceinline__ void load_row16(const float* __restrict__ p, float* __restrict__ x) {
    const float4* xp = (const float4*)p;
    float4 a = xp[0], b = xp[1], c = xp[2], d = xp[3];
    x[0]=a.x; x[1]=a.y; x[2]=a.z; x[3]=a.w;
    x[4]=b.x; x[5]=b.y; x[6]=b.z; x[7]=b.w;
    x[8]=c.x; x[9]=c.y; x[10]=c.z; x[11]=c.w;
    x[12]=d.x; x[13]=d.y; x[14]=d.z; x[15]=d.w;
}

// ---------------------------------------------------------------------------
// Layer 0: Z col 0 + logdet = -alpha0 (atomicAdd target for the layers).
// Separate dispatch: must complete before any layer block's atomicAdd, and
// block ordering within one dispatch is undefined (can't fold into gf_fused).
// ---------------------------------------------------------------------------
__global__ void gf_init(const float* __restrict__ X, const float* __restrict__ ip,
                        float* __restrict__ out) {
    int idx = blockIdx.x * blockDim.x + threadIdx.x;
    if (idx >= Bb * Nn) return;
    float mu = ip[0], alpha = ip[1];
    float x0 = X[(size_t)idx * Dd];
    out[(size_t)idx * Dd] = (x0 - mu) * __expf(-alpha);
    out[(size_t)Bb * Nn * Dd + idx] = -alpha;
}

// ---------------------------------------------------------------------------
// Fused: proj -> barrier -> per-wave flash attn (all 32x32x16 MFMA, dual
// 32-query streams/wave, 64 q/wave) -> epilogue. R9 structure (verified
// 63.0us) + T5 s_setprio(1) around the MFMA clusters: the 16 waves drift to
// independent loop phases (no barriers in the K-loop), so boosting a wave
// whose MFMA operands are ready lets it preempt waves in exp issue-holds.
// grid (NL, Bb), 1024 threads, rs via ones-column; P pack via v_perm trunc.
// ---------------------------------------------------------------------------
__launch_bounds__(1024, 4)
__global__ void gf_fused(const float* __restrict__ X,
                         const float* __restrict__ Wq, const float* __restrict__ bq,
                         const float* __restrict__ Wk, const float* __restrict__ bk,
                         const float* __restrict__ Wv, const float* __restrict__ bv,
                         const float* __restrict__ Wo, const float* __restrict__ bo,
                         const float* __restrict__ Wf, const float* __restrict__ bf,
                         float* __restrict__ out) {
    extern __shared__ char smem[];
    const int l = blockIdx.x, b = blockIdx.y, i = l + 1;
    const int t = threadIdx.x;
    const int wid = t >> 6, lane = t & 63;
    const int q31 = lane & 31, h = lane >> 5;
    const float qscale = 1.4426950408889634f * rsqrtf((float)i);

    unsigned short* Ksh  = (unsigned short*)smem;
    unsigned short* Vsh  = (unsigned short*)(smem + V_OFF);
    unsigned short* Ones = (unsigned short*)(smem + ONES_OFF);

    const float* Xb  = X  + (size_t)b * Nn * Dd;
    const float* wq  = Wq + l * 256;  const float* bql = bq + l * 16;
    const float* wk  = Wk + l * 256;  const float* bkl = bk + l * 16;
    const float* wvp = Wv + l * 256;  const float* bvl = bv + l * 16;
    const float* wo  = Wo + l * 256;  const float* bol = bo + l * 16;
    const float* wf  = Wf + l * 32;   const float* bfl = bf + l * 2;

    // ---------------- proj phase: thread t = row n = t ----------------
    unsigned qu[8];                       // Q row t, scaled, bf16 pairs (live
                                          // through loop; reused in epilogue)
    {
        float xr[16]; load_row16(Xb + (size_t)t * Dd, xr);
        float tmp[16];

        project(xr, wk, bkl, i, tmp);
        {
            unsigned u[8];
#pragma unroll
            for (int r = 0; r < 8; r++) u[r] = pack2bf(tmp[2*r], tmp[2*r+1]);
            uint4* kd = (uint4*)(Ksh + t * 16);
            kd[0] = make_uint4(u[0], u[1], u[2], u[3]);
            kd[1] = make_uint4(u[4], u[5], u[6], u[7]);
        }

        project(xr, wvp, bvl, i, tmp);
        {
            unsigned short* vcol = Vsh + (t & ~15) + vperm(t & 15);
#pragma unroll
            for (int d = 0; d < 16; d++) vcol[d * VSTR] = bf1(tmp[d]);
        }

        Ones[t] = 0x3F80;                 // bf16(1.0)

        project(xr, wq, bql, i, tmp);
#pragma unroll
        for (int r = 0; r < 8; r++) qu[r] = pack2bf(tmp[2*r] * qscale, tmp[2*r+1] * qscale);
    }
    __syncthreads();

    // ---- Q B-frags via same-wave shuffles (wave wid owns rows wid*64..+63) --
    short8 qf0, qf1;
    {
        unsigned d0[4], d1[4];
#pragma unroll
        for (int j = 0; j < 4; j++) {
            unsigned lo = __shfl(qu[j], q31);
            unsigned hi = __shfl(qu[4 + j], q31);
            d0[j] = h ? hi : lo;
            lo = __shfl(qu[j], 32 + q31);
            hi = __shfl(qu[4 + j], 32 + q31);
            d1[j] = h ? hi : lo;
        }
        uint4v v0 = {d0[0], d0[1], d0[2], d0[3]};
        uint4v v1 = {d1[0], d1[1], d1[2], d1[3]};
        qf0 = __builtin_bit_cast(short8, v0);
        qf1 = __builtin_bit_cast(short8, v1);
    }

    // ---------------- attention loop ----------------
    f32x16 zf16 = {};
    f32x16 D0 = {}, D1 = {};

    const unsigned short* Kp = Ksh + (size_t)q31 * 16 + h * 8;   // A: K[key][8h+j]
    // lanes q31<16: permuted V^T row d=q31; lanes q31>=16: ones (rs col 16).
    // 8h inside: one b128 = one B-frag.
    const unsigned short* Vp = ((q31 < 16) ? (Vsh + (size_t)q31 * VSTR) : Ones) + 8 * h;

    short8 kf  = *(const short8*)Kp;
    short8 vc0 = *(const short8*)(Vp);
    short8 vc1 = *(const short8*)(Vp + 16);

    for (int kb = 0; kb < Nn; kb += 32) {
        const int kn = (kb + 32) & (Nn - 1);
        short8 kfn = *(const short8*)(Kp + (size_t)kn * 16);
        short8 vn0 = *(const short8*)(Vp + kn);
        short8 vn1 = *(const short8*)(Vp + kn + 16);

        __builtin_amdgcn_s_setprio(1);
        f32x16 s0 = __builtin_amdgcn_mfma_f32_32x32x16_bf16(kf, qf0, zf16, 0, 0, 0);
        f32x16 s1 = __builtin_amdgcn_mfma_f32_32x32x16_bf16(kf, qf1, zf16, 0, 0, 0);
        __builtin_amdgcn_s_setprio(0);
        kf = kfn;

        // sub-chunk 0: S regs 0..7 (keys kb+{4h+0..3, 8+4h+0..3})
        {
            uint4v a0 = {expperm(s0[0], s0[1]), expperm(s0[2], s0[3]),
                         expperm(s0[4], s0[5]), expperm(s0[6], s0[7])};
            uint4v a1 = {expperm(s1[0], s1[1]), expperm(s1[2], s1[3]),
                         expperm(s1[4], s1[5]), expperm(s1[6], s1[7])};
            __builtin_amdgcn_s_setprio(1);
            D0 = __builtin_amdgcn_mfma_f32_32x32x16_bf16(
                     __builtin_bit_cast(short8, a0), vc0, D0, 0, 0, 0);
            D1 = __builtin_amdgcn_mfma_f32_32x32x16_bf16(
                     __builtin_bit_cast(short8, a1), vc0, D1, 0, 0, 0);
            __builtin_amdgcn_s_setprio(0);
        }
        // sub-chunk 1: S regs 8..15 (keys kb+16+{4h+0..3, 8+4h+0..3})
        {
            uint4v a0 = {expperm(s0[8], s0[9]),  expperm(s0[10], s0[11]),
                         expperm(s0[12], s0[13]), expperm(s0[14], s0[15])};
            uint4v a1 = {expperm(s1[8], s1[9]),  expperm(s1[10], s1[11]),
                         expperm(s1[12], s1[13]), expperm(s1[14], s1[15])};
            __builtin_amdgcn_s_setprio(1);
            D0 = __builtin_amdgcn_mfma_f32_32x32x16_bf16(
                     __builtin_bit_cast(short8, a0), vc1, D0, 0, 0, 0);
            D1 = __builtin_amdgcn_mfma_f32_32x32x16_bf16(
                     __builtin_bit_cast(short8, a1), vc1, D1, 0, 0, 0);
            __builtin_amdgcn_s_setprio(0);
        }
        vc0 = vn0; vc1 = vn1;
    }

    __syncthreads();   // all waves done with K/V/ones before O overlays them

    // ---- stage O (C-layout -> [q_local][d] stride 17) + rs; wave-local ----
    float* Ow = (float*)smem + wid * (64 * 17);
    if (q31 < 16) {
#pragma unroll
        for (int r = 0; r < 16; r++) {
            int m = (r & 3) + 8 * (r >> 2) + 4 * h;
            Ow[m * 17 + q31]        = D0[r];
            Ow[(m + 32) * 17 + q31] = D1[r];
        }
    }
    float* Rw = (float*)(smem + RS_OFF) + wid * 64;
    if (q31 == 16) {                      // col 16 of D = sum of P = rs
#pragma unroll
        for (int r = 0; r < 16; r++) {
            int m = (r & 3) + 8 * (r >> 2) + 4 * h;
            Rw[m]      = D0[r];
            Rw[32 + m] = D1[r];
        }
    }
    // same-wave LDS ops are in program order; epilogue reads own-wave data.

    // ---------------- epilogue (thread t = query n = t) ----------------
    {
        const float invq = 0.6931471805599453f * sqrtf((float)i);  // 1/qscale

        // reconstruct q from own qu (bf16-rounded, exactly what the MFMA saw)
        float a[16];
#pragma unroll
        for (int r = 0; r < 8; r++) {
            a[2*r]     = __uint_as_float(qu[r] << 16) * invq;
            a[2*r + 1] = __uint_as_float(qu[r] & 0xffff0000u) * invq;
        }

        const float* orow = (const float*)smem + wid * (64 * 17) + lane * 17;
        const float  inv  = 1.f / Rw[lane];
#pragma unroll
        for (int c = 0; c < 16; c++) a[c] += orow[c] * inv;

        float tt[16];
#pragma unroll
        for (int r = 0; r < 16; r++) {
            float acc = bol[r];
#pragma unroll
            for (int c = 0; c < 16; c++) acc = fmaf(a[c], wo[r * 16 + c], acc);
            tt[r] = fmaxf(acc, 0.f);
        }
#pragma unroll
        for (int r = 0; r < 16; r++) a[r] += (r < i) ? tt[r] : 0.f;

        float mu = bfl[0], al = bfl[1];
#pragma unroll
        for (int c = 0; c < 16; c++) {
            mu = fmaf(a[c], wf[c], mu);
            al = fmaf(a[c], wf[16 + c], al);
        }
        const float xi = Xb[(size_t)t * Dd + i];
        out[((size_t)(b * Nn + t)) * Dd + i] = (xi - mu) * __expf(-al);
        atomicAdd(out + (size_t)Bb * Nn * Dd + b * Nn + t, -al);
    }
}

// ---------------------------------------------------------------------------
// Fallback path (R1): fp32 kernel, if big dynamic LDS unavailable
// ---------------------------------------------------------------------------
__launch_bounds__(512, 2)
__global__ void gf_layer_fb(const float* __restrict__ X,
                            const float* __restrict__ Wq, const float* __restrict__ bq,
                            const float* __restrict__ Wk, const float* __restrict__ bk,
                            const float* __restrict__ Wv, const float* __restrict__ bv,
                            const float* __restrict__ Wo, const float* __restrict__ bo,
                            const float* __restrict__ Wf, const float* __restrict__ bf,
                            float* __restrict__ out) {
    const int l = blockIdx.x, b = blockIdx.y, i = l + 1, t = threadIdx.x;
    const float rscale = rsqrtf((float)i);
    __shared__ float Ksh[512 * 16];
    __shared__ float Vsh[512 * 16];
    const float* Xb = X + (size_t)b * Nn * Dd;
    const float* wq = Wq + l * 256; const float* wk = Wk + l * 256;
    const float* wv = Wv + l * 256; const float* wo = Wo + l * 256;
    const float* wf = Wf + l * 32;
    const float* bql = bq + l * 16; const float* bkl = bk + l * 16;
    const float* bvl = bv + l * 16; const float* bol = bo + l * 16;
    const float* bfl = bf + l * 2;
    const int n0 = t, n1 = t + 512;
    float q0[16], q1[16], xi0, xi1;
    {
        float xr[16];
        load_row16(Xb + (size_t)n0 * Dd, xr); xi0 = xr[i]; project(xr, wq, bql, i, q0);
        load_row16(Xb + (size_t)n1 * Dd, xr); xi1 = xr[i]; project(xr, wq, bql, i, q1);
    }
    float o0[16], o1[16];
#pragma unroll
    for (int c = 0; c < 16; c++) { o0[c] = 0.f; o1[c] = 0.f; }
    float ls0 = 0.f, ls1 = 0.f;
    for (int ch = 0; ch < 2; ch++) {
        float kr[16], vr[16];
        {
            float kx[16];
            load_row16(Xb + (size_t)(ch * 512 + t) * Dd, kx);
            project(kx, wk, bkl, i, kr);
            project(kx, wv, bvl, i, vr);
        }
        __syncthreads();
#pragma unroll
        for (int j = 0; j < 4; j++) {
            ((float4*)&Ksh[t * 16])[j] = ((float4*)kr)[j];
            ((float4*)&Vsh[t * 16])[j] = ((float4*)vr)[j];
        }
        __syncthreads();
        for (int k = 0; k < 512; k++) {
            float kk[16], vv[16];
#pragma unroll
            for (int j = 0; j < 4; j++) ((float4*)kk)[j] = ((const float4*)&Ksh[k * 16])[j];
            float s0 = 0.f, s1 = 0.f;
#pragma unroll
            for (int c = 0; c < 16; c++) { s0 = fmaf(q0[c], kk[c], s0); s1 = fmaf(q1[c], kk[c], s1); }
            float p0 = __expf(s0 * rscale), p1 = __expf(s1 * rscale);
            ls0 += p0; ls1 += p1;
#pragma unroll
            for (int j = 0; j < 4; j++) ((float4*)vv)[j] = ((const float4*)&Vsh[k * 16])[j];
#pragma unroll
            for (int c = 0; c < 16; c++) { o0[c] = fmaf(p0, vv[c], o0[c]); o1[c] = fmaf(p1, vv[c], o1[c]); }
        }
        __syncthreads();
    }
    float* logdet = out + (size_t)Bb * Nn * Dd;
#pragma unroll
    for (int rowsel = 0; rowsel < 2; rowsel++) {
        const float* qr = rowsel ? q1 : q0; const float* orr = rowsel ? o1 : o0;
        float lsum = rowsel ? ls1 : ls0; float xin = rowsel ? xi1 : xi0;
        int n = rowsel ? n1 : n0;
        float a[16]; float inv = 1.f / lsum;
#pragma unroll
        for (int c = 0; c < 16; c++) a[c] = qr[c] + orr[c] * inv;
        float tt[16];
#pragma unroll
        for (int r = 0; r < 16; r++) {
            float acc = bol[r];
#pragma unroll
            for (int c = 0; c < 16; c++) acc = fmaf(a[c], wo[r * 16 + c], acc);
            tt[r] = fmaxf(acc, 0.f);
        }
#pragma unroll
        for (int r = 0; r < 16; r++) a[r] += (r < i) ? tt[r] : 0.f;
        float mu = bfl[0], al = bfl[1];
#pragma unroll
        for (int c = 0; c < 16; c++) { mu = fmaf(a[c], wf[c], mu); al = fmaf(a[c], wf[16 + c], al); }
        out[((size_t)(b * Nn + n)) * Dd + i] = (xin - mu) * __expf(-al);
        atomicAdd(logdet + b * Nn + n, -al);
    }
}

extern "C" void kernel_launch(void* const* d_in, const int* in_sizes, int n_in,
                              void* d_out, int out_size, void* d_ws, size_t ws_size,
                              hipStream_t stream) {
    const float* X  = (const float*)d_in[0];
    const float* ip = (const float*)d_in[1];
    const float* Wq = (const float*)d_in[2];
    const float* bq = (const float*)d_in[3];
    const float* Wk = (const float*)d_in[4];
    const float* bk = (const float*)d_in[5];
    const float* Wv = (const float*)d_in[6];
    const float* bv = (const float*)d_in[7];
    const float* Wo = (const float*)d_in[8];
    const float* bo = (const float*)d_in[9];
    const float* Wf = (const float*)d_in[10];
    const float* bf = (const float*)d_in[11];
    float* out = (float*)d_out;

    gf_init<<<(Bb * Nn + 255) / 256, 256, 0, stream>>>(X, ip, out);

    hipError_t e = hipFuncSetAttribute((const void*)gf_fused,
                                       hipFuncAttributeMaxDynamicSharedMemorySize,
                                       LDS_TOTAL);
    if (e == hipSuccess) {
        gf_fused<<<dim3(NL, Bb), 1024, LDS_TOTAL, stream>>>(
            X, Wq, bq, Wk, bk, Wv, bv, Wo, bo, Wf, bf, out);
    } else {
        gf_layer_fb<<<dim3(NL, Bb), 512, 0, stream>>>(
            X, Wq, bq, Wk, bk, Wv, bv, Wo, bo, Wf, bf, out);
    }
}

// Round 7
// 134.318 us; speedup vs baseline: 1.2532x; 1.0040x over previous
//
#include <hip/hip_runtime.h>
#include <math.h>

#define Bb 16
#define Nn 1024
#define Dd 16
#define NL 15

typedef __attribute__((ext_vector_type(8))) short short8;
typedef __attribute__((ext_vector_type(16))) float f32x16;
typedef __attribute__((ext_vector_type(4))) unsigned uint4v;

#if __has_builtin(__builtin_amdgcn_exp2f)
#define EXP2(x) __builtin_amdgcn_exp2f(x)
#else
#define EXP2(x) exp2f(x)
#endif

// LDS layout (dynamic, DECLARED 81920 B — deliberately > 160KB/2 so the CP
// cannot co-schedule 2 blocks on one CU. R16 experiment: with 73728 B, two
// 72KB/64-VGPR blocks CAN pack per CU (147KB<=160KB); if the dispatcher does
// pack, 240 blocks land on ~120 CUs and ~136 CUs idle — which would explain
// the session-invariant ~2x gap between per-chunk issue accounting (~500cyc)
// and measured wall (~1211 cyc/chunk-slot at assumed 4 waves/SIMD spread).
// Used bytes (unchanged layout):
//   K    : [1024 keys][16 shorts]          offset 0      32768 B
//   V^T  : [16 d][VSTR=1040 shorts]        offset 32768  33280 B
//   ones : [1024 shorts] bf16(1.0)         offset 66048   2048 B
//   O    : 16 waves x [64 q][17 f32]       offset 0      69632 B (overlay)
//   rs   : 16 waves x [64 f32]             offset 69632   4096 B
// Session ledger: R10 qh-split spills(435us) | R11 split-kernels neutral attn,
// +30us overhead | R12/R13 pipelining neutral (latency not binding) | R14
// VALU-poly-exp slower (VALU issue near-binding; exp holds ARE counted in
// VALUBusy per R15 arithmetic) | R15 setprio +1.6us (reverted).
#define VSTR 1040
#define V_OFF 32768
#define ONES_OFF 66048
#define RS_OFF 69632
#define LDS_TOTAL 81920

// round-half-up fp32->bf16 (proj staging)
__device__ __forceinline__ unsigned pack2bf(float a, float b) {
    unsigned ua = __float_as_uint(a) + 0x8000u;
    unsigned ub = __float_as_uint(b) + 0x8000u;
    return (ua >> 16) | (ub & 0xffff0000u);
}
__device__ __forceinline__ unsigned short bf1(float a) {
    return (unsigned short)((__float_as_uint(a) + 0x8000u) >> 16);
}

// exp2 both, truncate-pack to bf16 pair in ONE v_perm_b32
__device__ __forceinline__ unsigned expperm(float x, float y) {
    unsigned ex = __float_as_uint(EXP2(x));
    unsigned ey = __float_as_uint(EXP2(y));
#if __has_builtin(__builtin_amdgcn_perm)
    return __builtin_amdgcn_perm(ey, ex, 0x07060302);   // {ey.hi16, ex.hi16}
#else
    return (ex >> 16) | (ey & 0xffff0000u);
#endif
}

// key permutation within a 16-block so a b128 at short-offset 8h yields keys
// {4h+0..3, 8+4h+0..3} (the 32x32x16 A-frag key order of the C->A identity)
__device__ __forceinline__ int vperm(int m) {
    return (m & 3) + ((m & 8) >> 1) + ((m & 4) << 1);
}

__device__ __forceinline__ void project(const float* __restrict__ xrow,
                                        const float* __restrict__ W,
                                        const float* __restrict__ bias,
                                        int i, float* __restrict__ q) {
#pragma unroll
    for (int r = 0; r < 16; r++) q[r] = 0.f;
    for (int c = 0; c < i; c++) {
        float xc = xrow[c];
#pragma unroll
        for (int r = 0; r < 16; r++) q[r] = fmaf(xc, W[r * 16 + c], q[r]);
    }
#pragma unroll
    for (int r = 0; r < 16; r++) q[r] = (r < i) ? (q[r] + bias[r]) : 0.f;
}

__device__ __forceinline__ void load_row16(const float* __restrict__ p, float* __restrict__ x) {
    const float4* xp = (const float4*)p;
    float4 a = xp[0], b = xp[1], c = xp[2], d = xp[3];
    x[0]=a.x; x[1]=a.y; x[2]=a.z; x[3]=a.w;
    x[4]=b.x; x[5]=b.y; x[6]=b.z; x[7]=b.w;
    x[8]=c.x; x[9]=c.y; x[10]=c.z; x[11]=c.w;
    x[12]=d.x; x[13]=d.y; x[14]=d.z; x[15]=d.w;
}

// ---------------------------------------------------------------------------
// Layer 0: Z col 0 + logdet = -alpha0 (atomicAdd target for the layers)
// ---------------------------------------------------------------------------
__global__ void gf_init(const float* __restrict__ X, const float* __restrict__ ip,
                        float* __restrict__ out) {
    int idx = blockIdx.x * blockDim.x + threadIdx.x;
    if (idx >= Bb * Nn) return;
    float mu = ip[0], alpha = ip[1];
    float x0 = X[(size_t)idx * Dd];
    out[(size_t)idx * Dd] = (x0 - mu) * __expf(-alpha);
    out[(size_t)Bb * Nn * Dd + idx] = -alpha;
}

// ---------------------------------------------------------------------------
// Fused: proj -> barrier -> per-wave flash attn (all 32x32x16 MFMA, dual
// 32-query streams/wave, 64 q/wave) -> epilogue. Exact R9 structure
// (verified 63.0us) — only the declared dynamic-LDS size differs (81920 B,
// anti-packing; see header comment).
// grid (NL, Bb), 1024 threads. rs via ones-column; P pack via v_perm trunc.
// ---------------------------------------------------------------------------
__launch_bounds__(1024, 4)
__global__ void gf_fused(const float* __restrict__ X,
                         const float* __restrict__ Wq, const float* __restrict__ bq,
                         const float* __restrict__ Wk, const float* __restrict__ bk,
                         const float* __restrict__ Wv, const float* __restrict__ bv,
                         const float* __restrict__ Wo, const float* __restrict__ bo,
                         const float* __restrict__ Wf, const float* __restrict__ bf,
                         float* __restrict__ out) {
    extern __shared__ char smem[];
    const int l = blockIdx.x, b = blockIdx.y, i = l + 1;
    const int t = threadIdx.x;
    const int wid = t >> 6, lane = t & 63;
    const int q31 = lane & 31, h = lane >> 5;
    const float qscale = 1.4426950408889634f * rsqrtf((float)i);

    unsigned short* Ksh  = (unsigned short*)smem;
    unsigned short* Vsh  = (unsigned short*)(smem + V_OFF);
    unsigned short* Ones = (unsigned short*)(smem + ONES_OFF);

    const float* Xb  = X  + (size_t)b * Nn * Dd;
    const float* wq  = Wq + l * 256;  const float* bql = bq + l * 16;
    const float* wk  = Wk + l * 256;  const float* bkl = bk + l * 16;
    const float* wvp = Wv + l * 256;  const float* bvl = bv + l * 16;
    const float* wo  = Wo + l * 256;  const float* bol = bo + l * 16;
    const float* wf  = Wf + l * 32;   const float* bfl = bf + l * 2;

    // ---------------- proj phase: thread t = row n = t ----------------
    unsigned qu[8];                       // Q row t, scaled, bf16 pairs (live
                                          // through loop; reused in epilogue)
    {
        float xr[16]; load_row16(Xb + (size_t)t * Dd, xr);
        float tmp[16];

        project(xr, wk, bkl, i, tmp);
        {
            unsigned u[8];
#pragma unroll
            for (int r = 0; r < 8; r++) u[r] = pack2bf(tmp[2*r], tmp[2*r+1]);
            uint4* kd = (uint4*)(Ksh + t * 16);
            kd[0] = make_uint4(u[0], u[1], u[2], u[3]);
            kd[1] = make_uint4(u[4], u[5], u[6], u[7]);
        }

        project(xr, wvp, bvl, i, tmp);
        {
            unsigned short* vcol = Vsh + (t & ~15) + vperm(t & 15);
#pragma unroll
            for (int d = 0; d < 16; d++) vcol[d * VSTR] = bf1(tmp[d]);
        }

        Ones[t] = 0x3F80;                 // bf16(1.0)

        project(xr, wq, bql, i, tmp);
#pragma unroll
        for (int r = 0; r < 8; r++) qu[r] = pack2bf(tmp[2*r] * qscale, tmp[2*r+1] * qscale);
    }
    __syncthreads();

    // ---- Q B-frags via same-wave shuffles (wave wid owns rows wid*64..+63) --
    short8 qf0, qf1;
    {
        unsigned d0[4], d1[4];
#pragma unroll
        for (int j = 0; j < 4; j++) {
            unsigned lo = __shfl(qu[j], q31);
            unsigned hi = __shfl(qu[4 + j], q31);
            d0[j] = h ? hi : lo;
            lo = __shfl(qu[j], 32 + q31);
            hi = __shfl(qu[4 + j], 32 + q31);
            d1[j] = h ? hi : lo;
        }
        uint4v v0 = {d0[0], d0[1], d0[2], d0[3]};
        uint4v v1 = {d1[0], d1[1], d1[2], d1[3]};
        qf0 = __builtin_bit_cast(short8, v0);
        qf1 = __builtin_bit_cast(short8, v1);
    }

    // ---------------- attention loop ----------------
    f32x16 zf16 = {};
    f32x16 D0 = {}, D1 = {};

    const unsigned short* Kp = Ksh + (size_t)q31 * 16 + h * 8;   // A: K[key][8h+j]
    // lanes q31<16: permuted V^T row d=q31; lanes q31>=16: ones (rs col 16).
    // 8h inside: one b128 = one B-frag.
    const unsigned short* Vp = ((q31 < 16) ? (Vsh + (size_t)q31 * VSTR) : Ones) + 8 * h;

    short8 kf  = *(const short8*)Kp;
    short8 vc0 = *(const short8*)(Vp);
    short8 vc1 = *(const short8*)(Vp + 16);

    for (int kb = 0; kb < Nn; kb += 32) {
        const int kn = (kb + 32) & (Nn - 1);
        short8 kfn = *(const short8*)(Kp + (size_t)kn * 16);
        short8 vn0 = *(const short8*)(Vp + kn);
        short8 vn1 = *(const short8*)(Vp + kn + 16);

        f32x16 s0 = __builtin_amdgcn_mfma_f32_32x32x16_bf16(kf, qf0, zf16, 0, 0, 0);
        f32x16 s1 = __builtin_amdgcn_mfma_f32_32x32x16_bf16(kf, qf1, zf16, 0, 0, 0);
        kf = kfn;

        // sub-chunk 0: S regs 0..7 (keys kb+{4h+0..3, 8+4h+0..3})
        {
            uint4v a0 = {expperm(s0[0], s0[1]), expperm(s0[2], s0[3]),
                         expperm(s0[4], s0[5]), expperm(s0[6], s0[7])};
            D0 = __builtin_amdgcn_mfma_f32_32x32x16_bf16(
                     __builtin_bit_cast(short8, a0), vc0, D0, 0, 0, 0);
            uint4v a1 = {expperm(s1[0], s1[1]), expperm(s1[2], s1[3]),
                         expperm(s1[4], s1[5]), expperm(s1[6], s1[7])};
            D1 = __builtin_amdgcn_mfma_f32_32x32x16_bf16(
                     __builtin_bit_cast(short8, a1), vc0, D1, 0, 0, 0);
        }
        // sub-chunk 1: S regs 8..15 (keys kb+16+{4h+0..3, 8+4h+0..3})
        {
            uint4v a0 = {expperm(s0[8], s0[9]),  expperm(s0[10], s0[11]),
                         expperm(s0[12], s0[13]), expperm(s0[14], s0[15])};
            D0 = __builtin_amdgcn_mfma_f32_32x32x16_bf16(
                     __builtin_bit_cast(short8, a0), vc1, D0, 0, 0, 0);
            uint4v a1 = {expperm(s1[8], s1[9]),  expperm(s1[10], s1[11]),
                         expperm(s1[12], s1[13]), expperm(s1[14], s1[15])};
            D1 = __builtin_amdgcn_mfma_f32_32x32x16_bf16(
                     __builtin_bit_cast(short8, a1), vc1, D1, 0, 0, 0);
        }
        vc0 = vn0; vc1 = vn1;
    }

    __syncthreads();   // all waves done with K/V/ones before O overlays them

    // ---- stage O (C-layout -> [q_local][d] stride 17) + rs; wave-local ----
    float* Ow = (float*)smem + wid * (64 * 17);
    if (q31 < 16) {
#pragma unroll
        for (int r = 0; r < 16; r++) {
            int m = (r & 3) + 8 * (r >> 2) + 4 * h;
            Ow[m * 17 + q31]        = D0[r];
            Ow[(m + 32) * 17 + q31] = D1[r];
        }
    }
    float* Rw = (float*)(smem + RS_OFF) + wid * 64;
    if (q31 == 16) {                      // col 16 of D = sum of P = rs
#pragma unroll
        for (int r = 0; r < 16; r++) {
            int m = (r & 3) + 8 * (r >> 2) + 4 * h;
            Rw[m]      = D0[r];
            Rw[32 + m] = D1[r];
        }
    }
    // same-wave LDS ops are in program order; epilogue reads own-wave data.

    // ---------------- epilogue (thread t = query n = t) ----------------
    {
        const float invq = 0.6931471805599453f * sqrtf((float)i);  // 1/qscale

        // reconstruct q from own qu (bf16-rounded, exactly what the MFMA saw)
        float a[16];
#pragma unroll
        for (int r = 0; r < 8; r++) {
            a[2*r]     = __uint_as_float(qu[r] << 16) * invq;
            a[2*r + 1] = __uint_as_float(qu[r] & 0xffff0000u) * invq;
        }

        const float* orow = (const float*)smem + wid * (64 * 17) + lane * 17;
        const float  inv  = 1.f / Rw[lane];
#pragma unroll
        for (int c = 0; c < 16; c++) a[c] += orow[c] * inv;

        float tt[16];
#pragma unroll
        for (int r = 0; r < 16; r++) {
            float acc = bol[r];
#pragma unroll
            for (int c = 0; c < 16; c++) acc = fmaf(a[c], wo[r * 16 + c], acc);
            tt[r] = fmaxf(acc, 0.f);
        }
#pragma unroll
        for (int r = 0; r < 16; r++) a[r] += (r < i) ? tt[r] : 0.f;

        float mu = bfl[0], al = bfl[1];
#pragma unroll
        for (int c = 0; c < 16; c++) {
            mu = fmaf(a[c], wf[c], mu);
            al = fmaf(a[c], wf[16 + c], al);
        }
        const float xi = Xb[(size_t)t * Dd + i];
        out[((size_t)(b * Nn + t)) * Dd + i] = (xi - mu) * __expf(-al);
        atomicAdd(out + (size_t)Bb * Nn * Dd + b * Nn + t, -al);
    }
}

// ---------------------------------------------------------------------------
// Fallback path (R1): fp32 kernel, if big dynamic LDS unavailable
// ---------------------------------------------------------------------------
__launch_bounds__(512, 2)
__global__ void gf_layer_fb(const float* __restrict__ X,
                            const float* __restrict__ Wq, const float* __restrict__ bq,
                            const float* __restrict__ Wk, const float* __restrict__ bk,
                            const float* __restrict__ Wv, const float* __restrict__ bv,
                            const float* __restrict__ Wo, const float* __restrict__ bo,
                            const float* __restrict__ Wf, const float* __restrict__ bf,
                            float* __restrict__ out) {
    const int l = blockIdx.x, b = blockIdx.y, i = l + 1, t = threadIdx.x;
    const float rscale = rsqrtf((float)i);
    __shared__ float Ksh[512 * 16];
    __shared__ float Vsh[512 * 16];
    const float* Xb = X + (size_t)b * Nn * Dd;
    const float* wq = Wq + l * 256; const float* wk = Wk + l * 256;
    const float* wv = Wv + l * 256; const float* wo = Wo + l * 256;
    const float* wf = Wf + l * 32;
    const float* bql = bq + l * 16; const float* bkl = bk + l * 16;
    const float* bvl = bv + l * 16; const float* bol = bo + l * 16;
    const float* bfl = bf + l * 2;
    const int n0 = t, n1 = t + 512;
    float q0[16], q1[16], xi0, xi1;
    {
        float xr[16];
        load_row16(Xb + (size_t)n0 * Dd, xr); xi0 = xr[i]; project(xr, wq, bql, i, q0);
        load_row16(Xb + (size_t)n1 * Dd, xr); xi1 = xr[i]; project(xr, wq, bql, i, q1);
    }
    float o0[16], o1[16];
#pragma unroll
    for (int c = 0; c < 16; c++) { o0[c] = 0.f; o1[c] = 0.f; }
    float ls0 = 0.f, ls1 = 0.f;
    for (int ch = 0; ch < 2; ch++) {
        float kr[16], vr[16];
        {
            float kx[16];
            load_row16(Xb + (size_t)(ch * 512 + t) * Dd, kx);
            project(kx, wk, bkl, i, kr);
            project(kx, wv, bvl, i, vr);
        }
        __syncthreads();
#pragma unroll
        for (int j = 0; j < 4; j++) {
            ((float4*)&Ksh[t * 16])[j] = ((float4*)kr)[j];
            ((float4*)&Vsh[t * 16])[j] = ((float4*)vr)[j];
        }
        __syncthreads();
        for (int k = 0; k < 512; k++) {
            float kk[16], vv[16];
#pragma unroll
            for (int j = 0; j < 4; j++) ((float4*)kk)[j] = ((const float4*)&Ksh[k * 16])[j];
            float s0 = 0.f, s1 = 0.f;
#pragma unroll
            for (int c = 0; c < 16; c++) { s0 = fmaf(q0[c], kk[c], s0); s1 = fmaf(q1[c], kk[c], s1); }
            float p0 = __expf(s0 * rscale), p1 = __expf(s1 * rscale);
            ls0 += p0; ls1 += p1;
#pragma unroll
            for (int j = 0; j < 4; j++) ((float4*)vv)[j] = ((const float4*)&Vsh[k * 16])[j];
#pragma unroll
            for (int c = 0; c < 16; c++) { o0[c] = fmaf(p0, vv[c], o0[c]); o1[c] = fmaf(p1, vv[c], o1[c]); }
        }
        __syncthreads();
    }
    float* logdet = out + (size_t)Bb * Nn * Dd;
#pragma unroll
    for (int rowsel = 0; rowsel < 2; rowsel++) {
        const float* qr = rowsel ? q1 : q0; const float* orr = rowsel ? o1 : o0;
        float lsum = rowsel ? ls1 : ls0; float xin = rowsel ? xi1 : xi0;
        int n = rowsel ? n1 : n0;
        float a[16]; float inv = 1.f / lsum;
#pragma unroll
        for (int c = 0; c < 16; c++) a[c] = qr[c] + orr[c] * inv;
        float tt[16];
#pragma unroll
        for (int r = 0; r < 16; r++) {
            float acc = bol[r];
#pragma unroll
            for (int c = 0; c < 16; c++) acc = fmaf(a[c], wo[r * 16 + c], acc);
            tt[r] = fmaxf(acc, 0.f);
        }
#pragma unroll
        for (int r = 0; r < 16; r++) a[r] += (r < i) ? tt[r] : 0.f;
        float mu = bfl[0], al = bfl[1];
#pragma unroll
        for (int c = 0; c < 16; c++) { mu = fmaf(a[c], wf[c], mu); al = fmaf(a[c], wf[16 + c], al); }
        out[((size_t)(b * Nn + n)) * Dd + i] = (xin - mu) * __expf(-al);
        atomicAdd(logdet + b * Nn + n, -al);
    }
}

extern "C" void kernel_launch(void* const* d_in, const int* in_sizes, int n_in,
                              void* d_out, int out_size, void* d_ws, size_t ws_size,
                              hipStream_t stream) {
    const float* X  = (const float*)d_in[0];
    const float* ip = (const float*)d_in[1];
    const float* Wq = (const float*)d_in[2];
    const float* bq = (const float*)d_in[3];
    const float* Wk = (const float*)d_in[4];
    const float* bk = (const float*)d_in[5];
    const float* Wv = (const float*)d_in[6];
    const float* bv = (const float*)d_in[7];
    const float* Wo = (const float*)d_in[8];
    const float* bo = (const float*)d_in[9];
    const float* Wf = (const float*)d_in[10];
    const float* bf = (const float*)d_in[11];
    float* out = (float*)d_out;

    gf_init<<<(Bb * Nn + 255) / 256, 256, 0, stream>>>(X, ip, out);

    hipError_t e = hipFuncSetAttribute((const void*)gf_fused,
                                       hipFuncAttributeMaxDynamicSharedMemorySize,
                                       LDS_TOTAL);
    if (e == hipSuccess) {
        gf_fused<<<dim3(NL, Bb), 1024, LDS_TOTAL, stream>>>(
            X, Wq, bq, Wk, bk, Wv, bv, Wo, bo, Wf, bf, out);
    } else {
        gf_layer_fb<<<dim3(NL, Bb), 512, 0, stream>>>(
            X, Wq, bq, Wk, bk, Wv, bv, Wo, bo, Wf, bf, out);
    }
}